// Round 12
// baseline (124.242 us; speedup 1.0000x reference)
//
#include <hip/hip_runtime.h>
#include <hip/hip_bf16.h>

#define IN_DIM 128
#define HEADS 4
#define ODIM 32
#define HD (HEADS * ODIM) // 128
#define NEG_SLOPE 0.2f

#define GM 64             // nodes per block in MFMA GEMM
#define LDK 136           // padded k-stride (bf16 elems)
#define ACCW 132          // fp32 acc LDS row stride

#define BIN_SHIFT 5
#define BIN_NODES 32      // dst nodes per bin
#define BINCAP 1024       // max edges per bin (mean 512)
#define SCAP 512          // staged edges per bin (LDS); overflow -> global path
#define ROWW 33           // LDS row stride in uints (bank-conflict pad)
#define MAXBINS 2048      // LDS sizing for bin branch (nbins = 1563)
#define KE 16             // edges per thread in bin branch

#define SMEM_BYTES 52224  // gemm staging need; >= bin 16KB and acc 33.8KB

typedef unsigned short ushortT;
typedef __attribute__((ext_vector_type(8))) short bf16x8;
typedef __attribute__((ext_vector_type(4))) float f32x4;

static __device__ __forceinline__ ushortT f2bf(float f) {
    __hip_bfloat16 b = __float2bfloat16(f); // RNE
    return *reinterpret_cast<ushortT*>(&b);
}
static __device__ __forceinline__ float hsel(float4 v, int head) {
    return (head == 0) ? v.x : (head == 1) ? v.y : (head == 2) ? v.z : v.w;
}
// signed-byte lane sh (0,8,16,24) of packed uint -> float
static __device__ __forceinline__ float i8f(unsigned int p, int sh) {
    return (float)((int)(p << (24 - sh)) >> 24);
}

// ---------------------------------------------------------------------------
// One-time W convert+transpose (Wt_g[c][k] = bf16(W[k][c])) + zero bin_cursor.
// ---------------------------------------------------------------------------
__global__ void __launch_bounds__(256) k_wconv_zero(
    const float* __restrict__ W, ushortT* __restrict__ Wt_g,
    int* __restrict__ bin_cursor, int nbins)
{
    const int idx = blockIdx.x * 256 + threadIdx.x;  // 0..16383
    const int c = idx >> 7, k = idx & 127;
    Wt_g[c * 128 + k] = f2bf(W[k * HD + c]);
    if (idx < nbins) bin_cursor[idx] = 0;
}

// ---------------------------------------------------------------------------
// Mega kernel (unchanged from r11): bin blocks + MFMA GEMM blocks with fused
// s_src/s_dst and int8-quantized h epilogues.
// ---------------------------------------------------------------------------
__global__ void __launch_bounds__(256) k_mega(
    const float* __restrict__ x, const ushortT* __restrict__ Wt_g,
    const float* __restrict__ a_src, const float* __restrict__ a_dst,
    const int* __restrict__ src, const int* __restrict__ dst,
    unsigned char* __restrict__ h8, float* __restrict__ scales,
    float* __restrict__ s_src, float* __restrict__ s_dst,
    int* __restrict__ bin_cursor, int* __restrict__ bin_buf,
    int N, int E, int nbins, int nBinBlocks)
{
    __shared__ __align__(16) char smem[SMEM_BYTES];
    const int t = threadIdx.x;

    if ((int)blockIdx.x < nBinBlocks) {
        // ---------------- bin branch ----------------
        int* lcnt = reinterpret_cast<int*>(smem);
        int* lcur = lcnt + MAXBINS;
        for (int i = t; i < nbins; i += 256) lcnt[i] = 0;
        __syncthreads();

        const int base_e = blockIdx.x * (256 * KE);
        int b_[KE]; int p_[KE];
#pragma unroll
        for (int k = 0; k < KE; ++k) {
            const int e = base_e + k * 256 + t;   // coalesced
            if (e < E) {
                const int d = dst[e];
                const int s = src[e];
                b_[k] = d >> BIN_SHIFT;
                p_[k] = ((d & (BIN_NODES - 1)) << 16) | s;
                atomicAdd(&lcnt[b_[k]], 1);
            } else {
                b_[k] = -1;
            }
        }
        __syncthreads();
        for (int i = t; i < nbins; i += 256) {
            const int c = lcnt[i];
            lcur[i] = (c > 0) ? atomicAdd(&bin_cursor[i], c) : 0;
        }
        __syncthreads();
#pragma unroll
        for (int k = 0; k < KE; ++k) {
            if (b_[k] >= 0) {
                const int pos = atomicAdd(&lcur[b_[k]], 1);
                if (pos < BINCAP) bin_buf[b_[k] * BINCAP + pos] = p_[k];
            }
        }
        return;
    }

    // ---------------- gemm branch ----------------
    ushortT* Xs = reinterpret_cast<ushortT*>(smem);
    ushortT* Wt = Xs + GM * LDK;

    const int n0 = ((int)blockIdx.x - nBinBlocks) * GM;

    {   // stage Wt: vector copy of pre-transposed bf16
#pragma unroll
        for (int it = 0; it < 8; ++it) {
            const int o = it * 2048 + t * 8;      // linear ushort offset
            *reinterpret_cast<uint4*>(&Wt[(o >> 7) * LDK + (o & 127)]) =
                *reinterpret_cast<const uint4*>(&Wt_g[o]);
        }
    }
    {   // stage x as bf16: Xs[r][k]
        const int r  = t >> 2;          // 0..63
        const int k0 = (t & 3) * 32;
        const int ng = n0 + r;
        if (ng < N) {
#pragma unroll
            for (int kk = 0; kk < 32; kk += 4) {
                float4 v = *reinterpret_cast<const float4*>(
                    &x[(size_t)ng * IN_DIM + k0 + kk]);
                ushort4 u;
                u.x = f2bf(v.x); u.y = f2bf(v.y); u.z = f2bf(v.z); u.w = f2bf(v.w);
                *reinterpret_cast<ushort4*>(&Xs[r * LDK + k0 + kk]) = u;
            }
        } else {
#pragma unroll
            for (int kk = 0; kk < 32; kk += 4)
                *reinterpret_cast<ushort4*>(&Xs[r * LDK + k0 + kk]) =
                    make_ushort4(0, 0, 0, 0);
        }
    }
    __syncthreads();

    const int w  = t >> 6;          // wave 0..3
    const int l  = t & 63;
    const int lr = l & 15;
    const int lk = (l >> 4) * 8;

    f32x4 acc[8];
#pragma unroll
    for (int i = 0; i < 8; ++i) acc[i] = (f32x4)(0.f);

#pragma unroll
    for (int kt = 0; kt < 4; ++kt) {
        const bf16x8 af = *reinterpret_cast<const bf16x8*>(
            &Xs[(w * 16 + lr) * LDK + kt * 32 + lk]);
#pragma unroll
        for (int ct = 0; ct < 8; ++ct) {
            const bf16x8 bfr = *reinterpret_cast<const bf16x8*>(
                &Wt[(ct * 16 + lr) * LDK + kt * 32 + lk]);
            acc[ct] = __builtin_amdgcn_mfma_f32_16x16x32_bf16(af, bfr, acc[ct],
                                                              0, 0, 0);
        }
    }

    // ---- s_src/s_dst epilogue ----
    float aSv[8], aDv[8];
#pragma unroll
    for (int ct = 0; ct < 8; ++ct) {
        aSv[ct] = a_src[ct * 16 + lr];
        aDv[ct] = a_dst[ct * 16 + lr];
    }
    const int rbase = w * 16 + (l >> 4) * 4;

#pragma unroll
    for (int j = 0; j < 4; ++j) {
        const int ng = n0 + rbase + j;
        float ps[4] = {0.f, 0.f, 0.f, 0.f}, pd[4] = {0.f, 0.f, 0.f, 0.f};
#pragma unroll
        for (int ct = 0; ct < 8; ++ct) {
            ps[ct >> 1] = fmaf(acc[ct][j], aSv[ct], ps[ct >> 1]);
            pd[ct >> 1] = fmaf(acc[ct][j], aDv[ct], pd[ct >> 1]);
        }
#pragma unroll
        for (int o = 1; o <= 8; o <<= 1) {
#pragma unroll
            for (int hh = 0; hh < 4; ++hh) {
                ps[hh] += __shfl_xor(ps[hh], o, 64);
                pd[hh] += __shfl_xor(pd[hh], o, 64);
            }
        }
        if (lr == 0 && ng < N) {
            *reinterpret_cast<float4*>(&s_src[ng * 4]) =
                make_float4(ps[0], ps[1], ps[2], ps[3]);
            *reinterpret_cast<float4*>(&s_dst[ng * 4]) =
                make_float4(pd[0], pd[1], pd[2], pd[3]);
        }
    }

    // ---- int8 h epilogue: LDS transpose -> row max -> quantize ----
    __syncthreads();
    float* accb = reinterpret_cast<float*>(smem);   // [GM][ACCW] fp32

#pragma unroll
    for (int ct = 0; ct < 8; ++ct)
#pragma unroll
        for (int j = 0; j < 4; ++j)
            accb[(rbase + j) * ACCW + ct * 16 + lr] = acc[ct][j];
    __syncthreads();

    {
        const int row = t >> 2;          // 0..63
        const int c0  = (t & 3) * 32;
        const int ng  = n0 + row;

        float4 v[8];
        float m = 0.f;
#pragma unroll
        for (int i = 0; i < 8; ++i) {
            v[i] = *reinterpret_cast<const float4*>(&accb[row * ACCW + c0 + 4 * i]);
            m = fmaxf(m, fmaxf(fmaxf(fabsf(v[i].x), fabsf(v[i].y)),
                               fmaxf(fabsf(v[i].z), fabsf(v[i].w))));
        }
        m = fmaxf(m, __shfl_xor(m, 1, 64));
        m = fmaxf(m, __shfl_xor(m, 2, 64));    // row max over the quad

        const float inv = (m > 0.f) ? 127.f / m : 0.f;
        unsigned int p[8];
#pragma unroll
        for (int i = 0; i < 8; ++i) {
            const int q0 = __float2int_rn(v[i].x * inv);
            const int q1 = __float2int_rn(v[i].y * inv);
            const int q2 = __float2int_rn(v[i].z * inv);
            const int q3 = __float2int_rn(v[i].w * inv);
            p[i] = (q0 & 0xFF) | ((q1 & 0xFF) << 8) |
                   ((q2 & 0xFF) << 16) | ((q3 & 0xFF) << 24);
        }
        if (ng < N) {
            *reinterpret_cast<uint4*>(&h8[(size_t)ng * 128 + c0]) =
                make_uint4(p[0], p[1], p[2], p[3]);
            *reinterpret_cast<uint4*>(&h8[(size_t)ng * 128 + c0 + 16]) =
                make_uint4(p[4], p[5], p[6], p[7]);
            if ((t & 3) == 0) scales[ng] = m * (1.f / 127.f);
        }
    }
}

// ---------------------------------------------------------------------------
// Pull, two-phase: (A) CSR scatter fused with per-edge exp/scale -> LDS, then
// cooperative staging of all <=SCAP int8 h-rows into LDS (max MLP, no
// dependent consume); (B) per-node compute reading only LDS. Overflow edges
// (pos >= SCAP, ~2%) take the old global path.
// ---------------------------------------------------------------------------
__global__ void __launch_bounds__(256) k_pull_binned(
    const int* __restrict__ bin_buf, const int* __restrict__ bin_cursor,
    const unsigned char* __restrict__ h8, const float* __restrict__ scales,
    const float* __restrict__ s_src, const float* __restrict__ s_dst,
    float* __restrict__ out, int N)
{
    __shared__ ushortT csr[BINCAP];                    // 2 KB
    __shared__ int cnt_s[BIN_NODES], start_s[BIN_NODES], cur_s[BIN_NODES];
    __shared__ unsigned int rows[SCAP * ROWW];         // 66 KB (padded stride)
    __shared__ float wexp[SCAP * HEADS];               // 8 KB
    __shared__ float wsc[SCAP];                        // 2 KB

    const int b = blockIdx.x;
    const int t = threadIdx.x;
    const int node0 = b << BIN_SHIFT;

    int nedge = bin_cursor[b];
    nedge = (nedge < BINCAP) ? nedge : BINCAP;

    const float4* ss4 = reinterpret_cast<const float4*>(s_src);
    const float4* sd4 = reinterpret_cast<const float4*>(s_dst);
    const unsigned int* hu = reinterpret_cast<const unsigned int*>(h8);

    if (t < BIN_NODES) cnt_s[t] = 0;
    __syncthreads();

    for (int i = t; i < nedge; i += 256)
        atomicAdd(&cnt_s[bin_buf[b * BINCAP + i] >> 16], 1);
    __syncthreads();

    if (t < 32) {
        const int v = cnt_s[t];
        int inc = v;
#pragma unroll
        for (int o = 1; o < 32; o <<= 1) {
            const int x = __shfl_up(inc, o, 32);
            if (t >= o) inc += x;
        }
        start_s[t] = inc - v;
        cur_s[t]   = inc - v;
    }
    __syncthreads();

    // scatter + fused per-edge exp/scale into LDS
    for (int i = t; i < nedge; i += 256) {
        const int p = bin_buf[b * BINCAP + i];
        const int s = p & 0xFFFF;
        const int dloc = p >> 16;
        const int pos = atomicAdd(&cur_s[dloc], 1);
        csr[pos] = (ushortT)s;
        if (pos < SCAP) {
            const float4 vs = ss4[s];
            const float4 vd = sd4[node0 + dloc];
            float e0 = vs.x + vd.x, e1 = vs.y + vd.y;
            float e2 = vs.z + vd.z, e3 = vs.w + vd.w;
            e0 = (e0 > 0.f) ? e0 : NEG_SLOPE * e0;
            e1 = (e1 > 0.f) ? e1 : NEG_SLOPE * e1;
            e2 = (e2 > 0.f) ? e2 : NEG_SLOPE * e2;
            e3 = (e3 > 0.f) ? e3 : NEG_SLOPE * e3;
            wexp[pos * 4 + 0] = __expf(e0);
            wexp[pos * 4 + 1] = __expf(e1);
            wexp[pos * 4 + 2] = __expf(e2);
            wexp[pos * 4 + 3] = __expf(e3);
            wsc[pos] = scales[s];
        }
    }
    __syncthreads();

    // cooperative row staging: ~independent uint4 copies, max MLP
    {
        const int cap = (nedge < SCAP) ? nedge : SCAP;
        const int sub = (t & 7) * 4;           // uint4 slot within 32-uint row
        for (int i = t >> 3; i < cap; i += 32) {
            const int s = csr[i];
            const uint4 v = *reinterpret_cast<const uint4*>(
                &hu[(size_t)s * 32 + sub]);
            *reinterpret_cast<uint4*>(&rows[i * ROWW + sub]) = v;
        }
    }
    __syncthreads();

    const int wv   = t >> 6;
    const int l    = t & 63;
    const int half = l >> 5;
    const int l32  = l & 31;
    const int head = l32 >> 3;
    const int hoff = head * 8 + (l32 & 7);   // uint index within 32-uint row

    for (int k = 0; k < 8; ++k) {
        const int nloc = wv * 8 + k;
        const int n = node0 + nloc;
        if (n >= N) break;

        const int st  = start_s[nloc];
        const int deg = cnt_s[nloc];
        const float4 vd4 = sd4[n];
        const float vd = hsel(vd4, head);

        float den = 0.f;
        float a0 = 0.f, a1 = 0.f, a2 = 0.f, a3 = 0.f;

        const int count = (deg - half + 1) >> 1;
        for (int j = 0; j < count; j += 4) {
#pragma unroll
            for (int m = 0; m < 4; ++m) {
                const bool vm = (j + m) < count;
                const int i0 = st + 2 * (vm ? (j + m) : j) + half;
                float ex, sc; unsigned int q;
                if (i0 < SCAP) {
                    ex = wexp[i0 * 4 + head];
                    sc = wsc[i0];
                    q  = rows[i0 * ROWW + hoff];
                } else {            // rare overflow: global path
                    const int s = csr[i0];
                    float e = hsel(ss4[s], head) + vd;
                    e = (e > 0.f) ? e : NEG_SLOPE * e;
                    ex = __expf(e);
                    sc = scales[s];
                    q  = hu[(size_t)s * 32 + hoff];
                }
                ex = vm ? ex : 0.f;
                den += ex;
                const float ws = ex * sc;
                a0 = fmaf(ws, i8f(q, 0), a0);
                a1 = fmaf(ws, i8f(q, 8), a1);
                a2 = fmaf(ws, i8f(q, 16), a2);
                a3 = fmaf(ws, i8f(q, 24), a3);
            }
        }

        // combine the two half-waves
        a0 += __shfl_xor(a0, 32, 64);
        a1 += __shfl_xor(a1, 32, 64);
        a2 += __shfl_xor(a2, 32, 64);
        a3 += __shfl_xor(a3, 32, 64);
        den += __shfl_xor(den, 32, 64);

        const float inv = 1.f / (den + 1e-12f);
        a0 *= inv; a1 *= inv; a2 *= inv; a3 *= inv;

        // head-mean across lanes (xor 8, 16 flips head bits)
        a0 += __shfl_xor(a0, 8, 64);  a0 += __shfl_xor(a0, 16, 64);
        a1 += __shfl_xor(a1, 8, 64);  a1 += __shfl_xor(a1, 16, 64);
        a2 += __shfl_xor(a2, 8, 64);  a2 += __shfl_xor(a2, 16, 64);
        a3 += __shfl_xor(a3, 8, 64);  a3 += __shfl_xor(a3, 16, 64);

        if (l < 8) {
            float4 o4 = make_float4(0.25f * a0, 0.25f * a1, 0.25f * a2, 0.25f * a3);
            *reinterpret_cast<float4*>(&out[(size_t)n * ODIM + l * 4]) = o4;
        }
    }
}

extern "C" void kernel_launch(void* const* d_in, const int* in_sizes, int n_in,
                              void* d_out, int out_size, void* d_ws, size_t ws_size,
                              hipStream_t stream)
{
    const float* x      = (const float*)d_in[0];
    const int*   eidx   = (const int*)d_in[1];
    const float* W      = (const float*)d_in[2];
    const float* a_src  = (const float*)d_in[3];
    const float* a_dst  = (const float*)d_in[4];
    float* out = (float*)d_out;

    const int N = in_sizes[0] / IN_DIM;
    const int E = in_sizes[1] / 2;
    const int* src = eidx;       // edge_index[0, :]
    const int* dst = eidx + E;   // edge_index[1, :]

    const int nbins = (N + BIN_NODES - 1) >> BIN_SHIFT;   // 1563 for N=50000

    // workspace: h8 6.4MB | scales .2MB | s_src .8MB | s_dst .8MB |
    //            Wt_g 32KB | bin_buf 6.4MB | bin_cursor 6.3KB  -> ~14.7MB
    char* wsp = (char*)d_ws;
    unsigned char* h8 = (unsigned char*)wsp; wsp += (size_t)N * 128;
    float* scales   = (float*)wsp;    wsp += (size_t)N * sizeof(float);
    float* s_src    = (float*)wsp;    wsp += (size_t)N * HEADS * sizeof(float);
    float* s_dst    = (float*)wsp;    wsp += (size_t)N * HEADS * sizeof(float);
    ushortT* Wt_g   = (ushortT*)wsp;  wsp += (size_t)128 * 128 * sizeof(ushortT);
    int* bin_buf    = (int*)wsp;      wsp += (size_t)nbins * BINCAP * sizeof(int);
    int* bin_cursor = (int*)wsp;      wsp += (size_t)nbins * sizeof(int);

    // 0) W convert/transpose + zero bin cursors
    k_wconv_zero<<<64, 256, 0, stream>>>(W, Wt_g, bin_cursor, nbins);

    // 1) mega: binning blocks first, then GEMM blocks
    {
        const int epb = 256 * KE;
        const int nBinBlocks  = (E + epb - 1) / epb;        // 196
        const int nGemmBlocks = (N + GM - 1) / GM;          // 782
        k_mega<<<nBinBlocks + nGemmBlocks, 256, 0, stream>>>(
            x, Wt_g, a_src, a_dst, src, dst,
            h8, scales, s_src, s_dst, bin_cursor, bin_buf,
            N, E, nbins, nBinBlocks);
    }

    // 2) per-bin two-phase pull (stage to LDS, then compute)
    k_pull_binned<<<nbins, 256, 0, stream>>>(bin_buf, bin_cursor, h8, scales,
                                             s_src, s_dst, out, N);
}

// Round 13
// 72.192 us; speedup vs baseline: 1.7210x; 1.7210x over previous
//
#include <hip/hip_runtime.h>
#include <hip/hip_bf16.h>

#define IN_DIM 128
#define HEADS 4
#define ODIM 32
#define HD (HEADS * ODIM) // 128
#define NEG_SLOPE 0.2f

#define GM 64             // nodes per block in MFMA GEMM
#define LDK 136           // padded k-stride (bf16 elems)
#define ACCW 132          // fp32 acc LDS row stride

#define BIN_SHIFT 4
#define BIN_NODES 16      // dst nodes per bin
#define BINCAP 512        // max edges per bin (mean 256, +16 sigma)
#define MAXBINS 4096      // LDS sizing for bin branch (nbins = 3125)
#define KE 16             // edges per thread in bin branch

#define SMEM_BYTES 52224  // gemm staging need; >= bin 32KB and acc 33.8KB

typedef unsigned short ushortT;
typedef __attribute__((ext_vector_type(8))) short bf16x8;
typedef __attribute__((ext_vector_type(4))) float f32x4;

static __device__ __forceinline__ ushortT f2bf(float f) {
    __hip_bfloat16 b = __float2bfloat16(f); // RNE
    return *reinterpret_cast<ushortT*>(&b);
}
static __device__ __forceinline__ float hsel(float4 v, int head) {
    return (head == 0) ? v.x : (head == 1) ? v.y : (head == 2) ? v.z : v.w;
}
// signed-byte lane sh (0,8,16,24) of packed uint -> float
static __device__ __forceinline__ float i8f(unsigned int p, int sh) {
    return (float)((int)(p << (24 - sh)) >> 24);
}

// ---------------------------------------------------------------------------
// One-time W convert+transpose (Wt_g[c][k] = bf16(W[k][c])) + zero bin_cursor.
// ---------------------------------------------------------------------------
__global__ void __launch_bounds__(256) k_wconv_zero(
    const float* __restrict__ W, ushortT* __restrict__ Wt_g,
    int* __restrict__ bin_cursor, int nbins)
{
    const int idx = blockIdx.x * 256 + threadIdx.x;  // 0..16383
    const int c = idx >> 7, k = idx & 127;
    Wt_g[c * 128 + k] = f2bf(W[k * HD + c]);
    if (idx < nbins) bin_cursor[idx] = 0;
}

// ---------------------------------------------------------------------------
// Mega kernel: bin blocks + MFMA GEMM blocks with fused s_src/s_dst and
// int8-quantized h epilogues (r11-proven; bins now 16 nodes wide).
// ---------------------------------------------------------------------------
__global__ void __launch_bounds__(256) k_mega(
    const float* __restrict__ x, const ushortT* __restrict__ Wt_g,
    const float* __restrict__ a_src, const float* __restrict__ a_dst,
    const int* __restrict__ src, const int* __restrict__ dst,
    unsigned char* __restrict__ h8, float* __restrict__ scales,
    float* __restrict__ s_src, float* __restrict__ s_dst,
    int* __restrict__ bin_cursor, int* __restrict__ bin_buf,
    int N, int E, int nbins, int nBinBlocks)
{
    __shared__ __align__(16) char smem[SMEM_BYTES];
    const int t = threadIdx.x;

    if ((int)blockIdx.x < nBinBlocks) {
        // ---------------- bin branch ----------------
        int* lcnt = reinterpret_cast<int*>(smem);
        int* lcur = lcnt + MAXBINS;
        for (int i = t; i < nbins; i += 256) lcnt[i] = 0;
        __syncthreads();

        const int base_e = blockIdx.x * (256 * KE);
        int b_[KE]; int p_[KE];
#pragma unroll
        for (int k = 0; k < KE; ++k) {
            const int e = base_e + k * 256 + t;   // coalesced
            if (e < E) {
                const int d = dst[e];
                const int s = src[e];
                b_[k] = d >> BIN_SHIFT;
                p_[k] = ((d & (BIN_NODES - 1)) << 16) | s;
                atomicAdd(&lcnt[b_[k]], 1);
            } else {
                b_[k] = -1;
            }
        }
        __syncthreads();
        for (int i = t; i < nbins; i += 256) {
            const int c = lcnt[i];
            lcur[i] = (c > 0) ? atomicAdd(&bin_cursor[i], c) : 0;
        }
        __syncthreads();
#pragma unroll
        for (int k = 0; k < KE; ++k) {
            if (b_[k] >= 0) {
                const int pos = atomicAdd(&lcur[b_[k]], 1);
                if (pos < BINCAP) bin_buf[b_[k] * BINCAP + pos] = p_[k];
            }
        }
        return;
    }

    // ---------------- gemm branch ----------------
    ushortT* Xs = reinterpret_cast<ushortT*>(smem);
    ushortT* Wt = Xs + GM * LDK;

    const int n0 = ((int)blockIdx.x - nBinBlocks) * GM;

    {   // stage Wt: vector copy of pre-transposed bf16
#pragma unroll
        for (int it = 0; it < 8; ++it) {
            const int o = it * 2048 + t * 8;      // linear ushort offset
            *reinterpret_cast<uint4*>(&Wt[(o >> 7) * LDK + (o & 127)]) =
                *reinterpret_cast<const uint4*>(&Wt_g[o]);
        }
    }
    {   // stage x as bf16: Xs[r][k]
        const int r  = t >> 2;          // 0..63
        const int k0 = (t & 3) * 32;
        const int ng = n0 + r;
        if (ng < N) {
#pragma unroll
            for (int kk = 0; kk < 32; kk += 4) {
                float4 v = *reinterpret_cast<const float4*>(
                    &x[(size_t)ng * IN_DIM + k0 + kk]);
                ushort4 u;
                u.x = f2bf(v.x); u.y = f2bf(v.y); u.z = f2bf(v.z); u.w = f2bf(v.w);
                *reinterpret_cast<ushort4*>(&Xs[r * LDK + k0 + kk]) = u;
            }
        } else {
#pragma unroll
            for (int kk = 0; kk < 32; kk += 4)
                *reinterpret_cast<ushort4*>(&Xs[r * LDK + k0 + kk]) =
                    make_ushort4(0, 0, 0, 0);
        }
    }
    __syncthreads();

    const int w  = t >> 6;          // wave 0..3
    const int l  = t & 63;
    const int lr = l & 15;
    const int lk = (l >> 4) * 8;

    f32x4 acc[8];
#pragma unroll
    for (int i = 0; i < 8; ++i) acc[i] = (f32x4)(0.f);

#pragma unroll
    for (int kt = 0; kt < 4; ++kt) {
        const bf16x8 af = *reinterpret_cast<const bf16x8*>(
            &Xs[(w * 16 + lr) * LDK + kt * 32 + lk]);
#pragma unroll
        for (int ct = 0; ct < 8; ++ct) {
            const bf16x8 bfr = *reinterpret_cast<const bf16x8*>(
                &Wt[(ct * 16 + lr) * LDK + kt * 32 + lk]);
            acc[ct] = __builtin_amdgcn_mfma_f32_16x16x32_bf16(af, bfr, acc[ct],
                                                              0, 0, 0);
        }
    }

    // ---- s_src/s_dst epilogue ----
    float aSv[8], aDv[8];
#pragma unroll
    for (int ct = 0; ct < 8; ++ct) {
        aSv[ct] = a_src[ct * 16 + lr];
        aDv[ct] = a_dst[ct * 16 + lr];
    }
    const int rbase = w * 16 + (l >> 4) * 4;

#pragma unroll
    for (int j = 0; j < 4; ++j) {
        const int ng = n0 + rbase + j;
        float ps[4] = {0.f, 0.f, 0.f, 0.f}, pd[4] = {0.f, 0.f, 0.f, 0.f};
#pragma unroll
        for (int ct = 0; ct < 8; ++ct) {
            ps[ct >> 1] = fmaf(acc[ct][j], aSv[ct], ps[ct >> 1]);
            pd[ct >> 1] = fmaf(acc[ct][j], aDv[ct], pd[ct >> 1]);
        }
#pragma unroll
        for (int o = 1; o <= 8; o <<= 1) {
#pragma unroll
            for (int hh = 0; hh < 4; ++hh) {
                ps[hh] += __shfl_xor(ps[hh], o, 64);
                pd[hh] += __shfl_xor(pd[hh], o, 64);
            }
        }
        if (lr == 0 && ng < N) {
            *reinterpret_cast<float4*>(&s_src[ng * 4]) =
                make_float4(ps[0], ps[1], ps[2], ps[3]);
            *reinterpret_cast<float4*>(&s_dst[ng * 4]) =
                make_float4(pd[0], pd[1], pd[2], pd[3]);
        }
    }

    // ---- int8 h epilogue: LDS transpose -> row max -> quantize ----
    __syncthreads();
    float* accb = reinterpret_cast<float*>(smem);   // [GM][ACCW] fp32

#pragma unroll
    for (int ct = 0; ct < 8; ++ct)
#pragma unroll
        for (int j = 0; j < 4; ++j)
            accb[(rbase + j) * ACCW + ct * 16 + lr] = acc[ct][j];
    __syncthreads();

    {
        const int row = t >> 2;          // 0..63
        const int c0  = (t & 3) * 32;
        const int ng  = n0 + row;

        float4 v[8];
        float m = 0.f;
#pragma unroll
        for (int i = 0; i < 8; ++i) {
            v[i] = *reinterpret_cast<const float4*>(&accb[row * ACCW + c0 + 4 * i]);
            m = fmaxf(m, fmaxf(fmaxf(fabsf(v[i].x), fabsf(v[i].y)),
                               fmaxf(fabsf(v[i].z), fabsf(v[i].w))));
        }
        m = fmaxf(m, __shfl_xor(m, 1, 64));
        m = fmaxf(m, __shfl_xor(m, 2, 64));    // row max over the quad

        const float inv = (m > 0.f) ? 127.f / m : 0.f;
        unsigned int p[8];
#pragma unroll
        for (int i = 0; i < 8; ++i) {
            const int q0 = __float2int_rn(v[i].x * inv);
            const int q1 = __float2int_rn(v[i].y * inv);
            const int q2 = __float2int_rn(v[i].z * inv);
            const int q3 = __float2int_rn(v[i].w * inv);
            p[i] = (q0 & 0xFF) | ((q1 & 0xFF) << 8) |
                   ((q2 & 0xFF) << 16) | ((q3 & 0xFF) << 24);
        }
        if (ng < N) {
            *reinterpret_cast<uint4*>(&h8[(size_t)ng * 128 + c0]) =
                make_uint4(p[0], p[1], p[2], p[3]);
            *reinterpret_cast<uint4*>(&h8[(size_t)ng * 128 + c0 + 16]) =
                make_uint4(p[4], p[5], p[6], p[7]);
            if ((t & 3) == 0) scales[ng] = m * (1.f / 127.f);
        }
    }
}

// ---------------------------------------------------------------------------
// Pull (r11 structure, 16-node bins): one block (256 thr) per bin; LDS CSR;
// each wave 4 nodes; two half-waves with 4-edge unroll -> 8 independent
// row-gathers in flight per wave. int8 h rows + per-row scale.
// ---------------------------------------------------------------------------
__global__ void __launch_bounds__(256) k_pull_binned(
    const int* __restrict__ bin_buf, const int* __restrict__ bin_cursor,
    const unsigned char* __restrict__ h8, const float* __restrict__ scales,
    const float* __restrict__ s_src, const float* __restrict__ s_dst,
    float* __restrict__ out, int N)
{
    __shared__ ushortT csr[BINCAP];
    __shared__ int cnt_s[BIN_NODES], start_s[BIN_NODES], cur_s[BIN_NODES];

    const int b = blockIdx.x;
    const int t = threadIdx.x;
    const int node0 = b << BIN_SHIFT;

    int nedge = bin_cursor[b];
    nedge = (nedge < BINCAP) ? nedge : BINCAP;

    if (t < BIN_NODES) cnt_s[t] = 0;
    __syncthreads();

    for (int i = t; i < nedge; i += 256)
        atomicAdd(&cnt_s[bin_buf[b * BINCAP + i] >> 16], 1);
    __syncthreads();

    if (t < BIN_NODES) {
        const int v = cnt_s[t];
        int inc = v;
#pragma unroll
        for (int o = 1; o < BIN_NODES; o <<= 1) {
            const int x = __shfl_up(inc, o, BIN_NODES);
            if (t >= o) inc += x;
        }
        start_s[t] = inc - v;
        cur_s[t]   = inc - v;
    }
    __syncthreads();

    for (int i = t; i < nedge; i += 256) {
        const int p = bin_buf[b * BINCAP + i];
        const int pos = atomicAdd(&cur_s[p >> 16], 1);
        csr[pos] = (ushortT)(p & 0xFFFF);
    }
    __syncthreads();

    const int wv   = t >> 6;
    const int l    = t & 63;
    const int half = l >> 5;
    const int l32  = l & 31;
    const int head = l32 >> 3;
    const int hoff = head * 8 + (l32 & 7);   // uint index within 32-uint row

    const unsigned int* hu = reinterpret_cast<const unsigned int*>(h8);
    const float4* ss4 = reinterpret_cast<const float4*>(s_src);

    for (int k = 0; k < 4; ++k) {
        const int nloc = wv * 4 + k;
        const int n = node0 + nloc;
        if (n >= N) break;

        const int st  = start_s[nloc];
        const int deg = cnt_s[nloc];
        const float4 vd4 = reinterpret_cast<const float4*>(s_dst)[n];
        const float vd = hsel(vd4, head);

        float den = 0.f;
        float a0 = 0.f, a1 = 0.f, a2 = 0.f, a3 = 0.f;

        const int count = (deg - half + 1) >> 1;
        for (int j = 0; j < count; j += 4) {
            const int i0 = st + 2 * j + half;
            const bool v1 = (j + 1) < count;
            const bool v2 = (j + 2) < count;
            const bool v3 = (j + 3) < count;
            const int s0 = csr[i0];
            const int s1 = v1 ? csr[i0 + 2] : s0;
            const int s2 = v2 ? csr[i0 + 4] : s0;
            const int s3 = v3 ? csr[i0 + 6] : s0;

            // issue all independent loads up front
            const float4 w0 = ss4[s0];
            const float4 w1 = ss4[s1];
            const float4 w2 = ss4[s2];
            const float4 w3 = ss4[s3];
            const float sc0 = scales[s0];
            const float sc1 = scales[s1];
            const float sc2 = scales[s2];
            const float sc3 = scales[s3];
            const unsigned int q0 = hu[(size_t)s0 * 32 + hoff];
            const unsigned int q1 = hu[(size_t)s1 * 32 + hoff];
            const unsigned int q2 = hu[(size_t)s2 * 32 + hoff];
            const unsigned int q3 = hu[(size_t)s3 * 32 + hoff];

            float e0 = hsel(w0, head) + vd;
            float e1 = hsel(w1, head) + vd;
            float e2 = hsel(w2, head) + vd;
            float e3 = hsel(w3, head) + vd;
            e0 = (e0 > 0.f) ? e0 : NEG_SLOPE * e0;
            e1 = (e1 > 0.f) ? e1 : NEG_SLOPE * e1;
            e2 = (e2 > 0.f) ? e2 : NEG_SLOPE * e2;
            e3 = (e3 > 0.f) ? e3 : NEG_SLOPE * e3;
            const float x0 = __expf(e0);
            const float x1 = v1 ? __expf(e1) : 0.f;
            const float x2 = v2 ? __expf(e2) : 0.f;
            const float x3 = v3 ? __expf(e3) : 0.f;

            den += (x0 + x1) + (x2 + x3);
            const float ws0 = x0 * sc0;
            const float ws1 = x1 * sc1;
            const float ws2 = x2 * sc2;
            const float ws3 = x3 * sc3;

            a0 = fmaf(ws0, i8f(q0, 0), a0);  a1 = fmaf(ws0, i8f(q0, 8), a1);
            a2 = fmaf(ws0, i8f(q0, 16), a2); a3 = fmaf(ws0, i8f(q0, 24), a3);
            a0 = fmaf(ws1, i8f(q1, 0), a0);  a1 = fmaf(ws1, i8f(q1, 8), a1);
            a2 = fmaf(ws1, i8f(q1, 16), a2); a3 = fmaf(ws1, i8f(q1, 24), a3);
            a0 = fmaf(ws2, i8f(q2, 0), a0);  a1 = fmaf(ws2, i8f(q2, 8), a1);
            a2 = fmaf(ws2, i8f(q2, 16), a2); a3 = fmaf(ws2, i8f(q2, 24), a3);
            a0 = fmaf(ws3, i8f(q3, 0), a0);  a1 = fmaf(ws3, i8f(q3, 8), a1);
            a2 = fmaf(ws3, i8f(q3, 16), a2); a3 = fmaf(ws3, i8f(q3, 24), a3);
        }

        // combine the two half-waves
        a0 += __shfl_xor(a0, 32, 64);
        a1 += __shfl_xor(a1, 32, 64);
        a2 += __shfl_xor(a2, 32, 64);
        a3 += __shfl_xor(a3, 32, 64);
        den += __shfl_xor(den, 32, 64);

        const float inv = 1.f / (den + 1e-12f);
        a0 *= inv; a1 *= inv; a2 *= inv; a3 *= inv;

        // head-mean across lanes (xor 8, 16 flips head bits)
        a0 += __shfl_xor(a0, 8, 64);  a0 += __shfl_xor(a0, 16, 64);
        a1 += __shfl_xor(a1, 8, 64);  a1 += __shfl_xor(a1, 16, 64);
        a2 += __shfl_xor(a2, 8, 64);  a2 += __shfl_xor(a2, 16, 64);
        a3 += __shfl_xor(a3, 8, 64);  a3 += __shfl_xor(a3, 16, 64);

        if (l < 8) {
            float4 o4 = make_float4(0.25f * a0, 0.25f * a1, 0.25f * a2, 0.25f * a3);
            *reinterpret_cast<float4*>(&out[(size_t)n * ODIM + l * 4]) = o4;
        }
    }
}

extern "C" void kernel_launch(void* const* d_in, const int* in_sizes, int n_in,
                              void* d_out, int out_size, void* d_ws, size_t ws_size,
                              hipStream_t stream)
{
    const float* x      = (const float*)d_in[0];
    const int*   eidx   = (const int*)d_in[1];
    const float* W      = (const float*)d_in[2];
    const float* a_src  = (const float*)d_in[3];
    const float* a_dst  = (const float*)d_in[4];
    float* out = (float*)d_out;

    const int N = in_sizes[0] / IN_DIM;
    const int E = in_sizes[1] / 2;
    const int* src = eidx;       // edge_index[0, :]
    const int* dst = eidx + E;   // edge_index[1, :]

    const int nbins = (N + BIN_NODES - 1) >> BIN_SHIFT;   // 3125 for N=50000

    // workspace: h8 6.4MB | scales .2MB | s_src .8MB | s_dst .8MB |
    //            Wt_g 32KB | bin_buf 6.4MB | bin_cursor 12.5KB  -> ~14.7MB
    char* wsp = (char*)d_ws;
    unsigned char* h8 = (unsigned char*)wsp; wsp += (size_t)N * 128;
    float* scales   = (float*)wsp;    wsp += (size_t)N * sizeof(float);
    float* s_src    = (float*)wsp;    wsp += (size_t)N * HEADS * sizeof(float);
    float* s_dst    = (float*)wsp;    wsp += (size_t)N * HEADS * sizeof(float);
    ushortT* Wt_g   = (ushortT*)wsp;  wsp += (size_t)128 * 128 * sizeof(ushortT);
    int* bin_buf    = (int*)wsp;      wsp += (size_t)nbins * BINCAP * sizeof(int);
    int* bin_cursor = (int*)wsp;      wsp += (size_t)nbins * sizeof(int);

    // 0) W convert/transpose + zero bin cursors
    k_wconv_zero<<<64, 256, 0, stream>>>(W, Wt_g, bin_cursor, nbins);

    // 1) mega: binning blocks first, then GEMM blocks
    {
        const int epb = 256 * KE;
        const int nBinBlocks  = (E + epb - 1) / epb;        // 196
        const int nGemmBlocks = (N + GM - 1) / GM;          // 782
        k_mega<<<nBinBlocks + nGemmBlocks, 256, 0, stream>>>(
            x, Wt_g, a_src, a_dst, src, dst,
            h8, scales, s_src, s_dst, bin_cursor, bin_buf,
            N, E, nbins, nBinBlocks);
    }

    // 2) per-bin LDS CSR + pull (int8 h, 16-node bins -> 3125 blocks)
    k_pull_binned<<<nbins, 256, 0, stream>>>(bin_buf, bin_cursor, h8, scales,
                                             s_src, s_dst, out, N);
}